// Round 3
// baseline (205.436 us; speedup 1.0000x reference)
//
#include <hip/hip_runtime.h>

// (B,T,U) = (32,1024,1024). Gates are ELEMENT-WISE (w_gates is a 4U vector),
// and i,f,g,o depend only on x_t -> c recurrence is linear:
//   c_t = f_t*c_{t-1} + i_t*g_t  (affine in c), composable per chunk as (F,P).
// Only h_T = o_T*tanh(c_T) feeds the dense layer -> out[b] = sum_u h*wd + bd.
#define BB 32
#define TT 1024
#define UU 1024
#define CHUNKS 32
#define LCH (TT / CHUNKS)   // 32 timesteps per chunk
#define U4 (UU / 4)         // 256 float4 per row

#define LOG2E 1.44269504088896340736f

__device__ __forceinline__ float fast_rcp(float x)  { return __builtin_amdgcn_rcpf(x); }
__device__ __forceinline__ float fast_exp2(float x) { return __builtin_amdgcn_exp2f(x); }

// Pre-scaled gate evaluators: caller folds log2e (and sign) into w',b'.
// sigmoid(w*x+b)  = 1/(1 + 2^(w'*x + b'))        with w' = -w*log2e, b' = -b*log2e
// tanh(w*x+b)     = 1 - 2/(1 + 2^(w''*x + b''))  with w'' = 2*w*log2e, b'' = 2*b*log2e
__device__ __forceinline__ float sig_pre(float wp, float x, float bp) {
    return fast_rcp(1.0f + fast_exp2(fmaf(wp, x, bp)));
}
__device__ __forceinline__ float tanh_pre(float wp, float x, float bp) {
    return fmaf(-2.0f, fast_rcp(1.0f + fast_exp2(fmaf(wp, x, bp))), 1.0f);
}

__device__ __forceinline__ void step1(float xv,
                                      float wi, float bi, float wf, float bf,
                                      float wg, float bg, float& F, float& P) {
    const float ig = sig_pre(wi, xv, bi);
    const float fg = sig_pre(wf, xv, bf);
    const float gg = tanh_pre(wg, xv, bg);
    P = fmaf(fg, P, ig * gg);
    F *= fg;
}

// Kernel 1: per-(b, u4, chunk) affine-map reduction, float4-vectorized.
// idx = chunk*B*U4 + b*U4 + u4 -> consecutive lanes read consecutive float4 u.
__global__ __launch_bounds__(256) void lstm_chunk_kernel(
    const float4* __restrict__ x,        // [B,T,U4]
    const float4* __restrict__ w_gates,  // [4*U4]
    const float4* __restrict__ b_gates,  // [4*U4]
    float4* __restrict__ Fout,           // [CHUNKS*B*U4]
    float4* __restrict__ Pout)           // [CHUNKS*B*U4]
{
    const int idx   = blockIdx.x * 256 + threadIdx.x;
    const int u4    = idx & (U4 - 1);
    const int b     = (idx >> 8) & (BB - 1);
    const int chunk = idx >> 13;

    float4 wi = w_gates[u4];
    float4 wf = w_gates[U4 + u4];
    float4 wg = w_gates[2 * U4 + u4];
    float4 bi = b_gates[u4];
    float4 bf = b_gates[U4 + u4];
    float4 bg = b_gates[2 * U4 + u4];
    // pre-scale: sigmoid args negated*log2e, tanh args *2*log2e
    wi.x *= -LOG2E; wi.y *= -LOG2E; wi.z *= -LOG2E; wi.w *= -LOG2E;
    bi.x *= -LOG2E; bi.y *= -LOG2E; bi.z *= -LOG2E; bi.w *= -LOG2E;
    wf.x *= -LOG2E; wf.y *= -LOG2E; wf.z *= -LOG2E; wf.w *= -LOG2E;
    bf.x *= -LOG2E; bf.y *= -LOG2E; bf.z *= -LOG2E; bf.w *= -LOG2E;
    wg.x *= 2*LOG2E; wg.y *= 2*LOG2E; wg.z *= 2*LOG2E; wg.w *= 2*LOG2E;
    bg.x *= 2*LOG2E; bg.y *= 2*LOG2E; bg.z *= 2*LOG2E; bg.w *= 2*LOG2E;

    const float4* xp = x + ((size_t)b * TT + (size_t)chunk * LCH) * U4 + u4;

    float4 F = make_float4(1.f, 1.f, 1.f, 1.f);
    float4 P = make_float4(0.f, 0.f, 0.f, 0.f);
#pragma unroll 8
    for (int j = 0; j < LCH; ++j) {
        const float4 xv = xp[(size_t)j * U4];
        step1(xv.x, wi.x, bi.x, wf.x, bf.x, wg.x, bg.x, F.x, P.x);
        step1(xv.y, wi.y, bi.y, wf.y, bf.y, wg.y, bg.y, F.y, P.y);
        step1(xv.z, wi.z, bi.z, wf.z, bf.z, wg.z, bg.z, F.z, P.z);
        step1(xv.w, wi.w, bi.w, wf.w, bf.w, wg.w, bg.w, F.w, P.w);
    }
    Fout[idx] = F;
    Pout[idx] = P;
}

// Kernel 2: fold chunk affine maps, final output gate, dense reduction.
__global__ __launch_bounds__(256) void lstm_final_kernel(
    const float4* __restrict__ Fin,      // [CHUNKS*B*U4]
    const float4* __restrict__ Pin,
    const float4* __restrict__ x,        // [B,T,U4]
    const float4* __restrict__ w_gates,
    const float4* __restrict__ b_gates,
    const float4* __restrict__ w_dense,  // [U4]
    const float* __restrict__ b_dense,   // [1]
    float* __restrict__ out)             // [B]
{
    const int b   = blockIdx.x;
    const int tid = threadIdx.x;         // tid == u4

    float4 c = make_float4(0.f, 0.f, 0.f, 0.f);
#pragma unroll
    for (int ch = 0; ch < CHUNKS; ++ch) {
        const size_t o = (size_t)ch * BB * U4 + (size_t)b * U4 + tid;
        const float4 F = Fin[o];
        const float4 P = Pin[o];
        c.x = fmaf(F.x, c.x, P.x);
        c.y = fmaf(F.y, c.y, P.y);
        c.z = fmaf(F.z, c.z, P.z);
        c.w = fmaf(F.w, c.w, P.w);
    }

    const float4 xv = x[((size_t)b * TT + (TT - 1)) * U4 + tid];
    float4 wo = w_gates[3 * U4 + tid];
    float4 bo = b_gates[3 * U4 + tid];
    wo.x *= -LOG2E; wo.y *= -LOG2E; wo.z *= -LOG2E; wo.w *= -LOG2E;
    bo.x *= -LOG2E; bo.y *= -LOG2E; bo.z *= -LOG2E; bo.w *= -LOG2E;
    const float4 wd = w_dense[tid];

    // h = sigmoid(o_arg) * tanh(c);  tanh via 2^(2x*log2e)
    float sum;
    {
        const float hx = sig_pre(wo.x, xv.x, bo.x) *
                         fmaf(-2.0f, fast_rcp(1.0f + fast_exp2(2.f * LOG2E * c.x)), 1.0f);
        const float hy = sig_pre(wo.y, xv.y, bo.y) *
                         fmaf(-2.0f, fast_rcp(1.0f + fast_exp2(2.f * LOG2E * c.y)), 1.0f);
        const float hz = sig_pre(wo.z, xv.z, bo.z) *
                         fmaf(-2.0f, fast_rcp(1.0f + fast_exp2(2.f * LOG2E * c.z)), 1.0f);
        const float hw = sig_pre(wo.w, xv.w, bo.w) *
                         fmaf(-2.0f, fast_rcp(1.0f + fast_exp2(2.f * LOG2E * c.w)), 1.0f);
        sum = hx * wd.x + hy * wd.y + hz * wd.z + hw * wd.w;
    }

    __shared__ float red[256];
    red[tid] = sum;
    __syncthreads();
#pragma unroll
    for (int s = 128; s > 0; s >>= 1) {
        if (tid < s) red[tid] += red[tid + s];
        __syncthreads();
    }
    if (tid == 0) out[b] = red[0] + b_dense[0];
}

extern "C" void kernel_launch(void* const* d_in, const int* in_sizes, int n_in,
                              void* d_out, int out_size, void* d_ws, size_t ws_size,
                              hipStream_t stream) {
    const float4* x       = (const float4*)d_in[0];
    const float4* w_gates = (const float4*)d_in[1];
    const float4* b_gates = (const float4*)d_in[2];
    const float4* w_dense = (const float4*)d_in[3];
    const float* b_dense  = (const float*)d_in[4];
    float* out = (float*)d_out;

    float4* Fout = (float4*)d_ws;                                         // 4 MB
    float4* Pout = (float4*)((char*)d_ws + (size_t)CHUNKS * BB * UU * 4); // +4 MB

    const int total = CHUNKS * BB * U4;           // 262144 threads
    lstm_chunk_kernel<<<total / 256, 256, 0, stream>>>(x, w_gates, b_gates, Fout, Pout);
    lstm_final_kernel<<<BB, 256, 0, stream>>>(Fout, Pout, x, w_gates, b_gates,
                                              w_dense, b_dense, out);
}